// Round 3
// baseline (99.003 us; speedup 1.0000x reference)
//
#include <hip/hip_runtime.h>

#define GH 32
#define GW 32
#define PITCH 36                    // dword row pitch -> every row base 16B-aligned
#define DNP (34 * PITCH + 4)        // 1228 floats; covers halo cell (32,32); 1228%4==0
#define WNP (GH * PITCH)            // 1152 floats, same pitch, interior at col 4
#define INFV 1000000000.0f
#define EPSV 1e-6f

// LDS layout: logical cell (r,c), r,c in [-1,32], lives at (r+1)*PITCH + 4 + c.
// Left halo = col 3, right halo = col 36 (spills into next row's unused cols 0-2).
// Everything init'd to INFV, so all halos read exactly 1e9f (matches reference pad).

__global__ __launch_bounds__(64)
void bbastar_kernel(const float* __restrict__ weights,
                    const int* __restrict__ source,
                    const int* __restrict__ target,
                    float* __restrict__ out) {
    __shared__ float d[2][DNP];
    __shared__ float wl[2][WNP];

    const int lane = threadIdx.x;
    const int sb   = lane >> 5;            // sub-batch within block (0/1)
    const int r    = lane & 31;            // owned row
    const int gb   = blockIdx.x * 2 + sb;  // global batch

    // ---- stage weights (+EPS, single f32 add as reference) coalesced into LDS ----
    {
        const float4* wg = (const float4*)(weights + (size_t)blockIdx.x * 2048);
        #pragma unroll
        for (int i = 0; i < 8; ++i) {
            const int idx = lane + i * 64;         // 0..511 float4s
            float4 v = wg[idx];
            const int fi = idx << 2;
            const int bb = fi >> 10;
            const int rr = (fi >> 5) & 31;
            const int cc = fi & 31;
            *(float4*)&wl[bb][rr * PITCH + 4 + cc] =
                make_float4(v.x + EPSV, v.y + EPSV, v.z + EPSV, v.w + EPSV);
        }
    }
    // ---- INF-fill dist (both batches, incl. halos) ----
    {
        const float4 inf4 = make_float4(INFV, INFV, INFV, INFV);
        float4* df4 = (float4*)&d[0][0];           // 2*1228/4 = 614 float4s
        #pragma unroll
        for (int i = 0; i < 10; ++i) {
            const int idx = lane + i * 64;
            if (idx < 614) df4[idx] = inf4;
        }
    }
    // ---- zero this block's output region (harness poisons with 0xAA) ----
    {
        const float4 z = make_float4(0.f, 0.f, 0.f, 0.f);
        float4* og = (float4*)(out + (size_t)blockIdx.x * 2048);
        #pragma unroll
        for (int i = 0; i < 8; ++i) og[lane + i * 64] = z;
    }

    const int sr = source[2 * gb], sc = source[2 * gb + 1];
    __syncthreads();
    if (r == 0)   // lanes 0 and 32: seed each batch's source cell
        d[sb][(sr + 1) * PITCH + 4 + sc] = wl[sb][sr * PITCH + 4 + sc];
    __syncthreads();

    // ---- per-lane register state: own row dist + weights ----
    float w[32], own[32];
    {
        const float4* wr = (const float4*)&wl[sb][r * PITCH + 4];
        const float4* dr = (const float4*)&d[sb][(r + 1) * PITCH + 4];
        #pragma unroll
        for (int k = 0; k < 8; ++k) {
            const float4 v = wr[k];
            w[4*k] = v.x; w[4*k+1] = v.y; w[4*k+2] = v.z; w[4*k+3] = v.w;
            const float4 o = dr[k];
            own[4*k] = o.x; own[4*k+1] = o.y; own[4*k+2] = o.z; own[4*k+3] = o.w;
        }
    }
    float* db = d[sb];
    const int topb = r * PITCH + 3;          // logical (r-1, -1)
    const int botb = (r + 2) * PITCH + 3;    // logical (r+1, -1)
    const int ownb = (r + 1) * PITCH + 4;    // logical (r, 0)

    // ---- relaxation to the unique least fixed point ----
    // Single wave: lockstep gives Jacobi across rows (reads precede writes in
    // program order); in-register GS along the row, direction alternating.
    // Any schedule converges to the same float32 least fixed point as the
    // reference's 1024 Jacobi sweeps (monotone map, walk-sum values); a sweep
    // with zero changes anywhere is a full Jacobi fixed-point certificate.
    for (int it = 0; it < 1200; ++it) {
        float top[34], bot[34];
        top[0] = db[topb];  bot[0] = db[botb];
        #pragma unroll
        for (int k = 0; k < 8; ++k) {
            const float4 t = *(const float4*)&db[topb + 1 + 4*k];
            top[1+4*k] = t.x; top[2+4*k] = t.y; top[3+4*k] = t.z; top[4+4*k] = t.w;
            const float4 bo = *(const float4*)&db[botb + 1 + 4*k];
            bot[1+4*k] = bo.x; bot[2+4*k] = bo.y; bot[3+4*k] = bo.z; bot[4+4*k] = bo.w;
        }
        top[33] = db[topb + 33];  bot[33] = db[botb + 33];

        float mx = 0.0f;
        if ((it & 1) == 0) {                 // forward GS
            float left = INFV;
            #pragma unroll
            for (int c = 0; c < 32; ++c) {
                const float oldr = (c < 31) ? own[c+1] : INFV;
                const float m1 = fminf(fminf(top[c], top[c+1]), top[c+2]);
                const float m2 = fminf(fminf(bot[c], bot[c+1]), bot[c+2]);
                const float m  = fminf(fminf(m1, m2), oldr);
                const float a  = fminf(own[c], w[c] + m);   // w + min == min of (w+·)
                const float nd = fminf(a, w[c] + left);
                mx   = fmaxf(mx, own[c] - nd);              // >0 iff changed
                own[c] = nd;
                left = nd;
            }
        } else {                              // backward GS
            float right = INFV;
            #pragma unroll
            for (int c = 31; c >= 0; --c) {
                const float oldl = (c > 0) ? own[c-1] : INFV;
                const float m1 = fminf(fminf(top[c], top[c+1]), top[c+2]);
                const float m2 = fminf(fminf(bot[c], bot[c+1]), bot[c+2]);
                const float m  = fminf(fminf(m1, m2), oldl);
                const float a  = fminf(own[c], w[c] + m);
                const float nd = fminf(a, w[c] + right);
                mx    = fmaxf(mx, own[c] - nd);
                own[c] = nd;
                right = nd;
            }
        }
        #pragma unroll
        for (int k = 0; k < 8; ++k)
            *(float4*)&db[ownb + 4*k] =
                make_float4(own[4*k], own[4*k+1], own[4*k+2], own[4*k+3]);

        const unsigned long long bal = __ballot(mx > 0.0f);
        __syncthreads();                      // single wave: just a waitcnt
        if (bal == 0ULL) break;               // both batches certified stable
    }

    // ---- greedy backtrack, lanes 0 (batch A) and 32 (batch B) in parallel ----
    // Halos hold exactly INFV = reference's where(valid,·,INF); strict '<' scan
    // in OFFS order replicates jnp.argmin first-min tie-breaking.
    if (r == 0) {
        const int drr[8] = {-1, -1, -1,  0, 0,  1, 1, 1};
        const int dcc[8] = {-1,  0,  1, -1, 1, -1, 0, 1};
        int pr = target[2 * gb];
        int pc = target[2 * gb + 1];
        float* ob = out + (size_t)gb * 1024;
        for (int step = 0; step < GH * GW; ++step) {
            ob[pr * GW + pc] = 1.0f;
            if (pr == sr && pc == sc) break;
            float best = INFV; int bj = 0;
            #pragma unroll
            for (int j = 0; j < 8; ++j) {
                const float v = db[(pr + drr[j] + 1) * PITCH + 4 + (pc + dcc[j])];
                if (v < best) { best = v; bj = j; }
            }
            pr += drr[bj];
            pc += dcc[bj];
        }
    }
}

extern "C" void kernel_launch(void* const* d_in, const int* in_sizes, int n_in,
                              void* d_out, int out_size, void* d_ws, size_t ws_size,
                              hipStream_t stream) {
    const float* weights = (const float*)d_in[0];
    const int*   source  = (const int*)d_in[1];
    const int*   target  = (const int*)d_in[2];
    float*       out     = (float*)d_out;
    const int B = in_sizes[0] / (GH * GW);
    bbastar_kernel<<<B / 2, 64, 0, stream>>>(weights, source, target, out);
}